// Round 1
// baseline (610.623 us; speedup 1.0000x reference)
//
#include <hip/hip_runtime.h>
#include <cstdint>
#include <cmath>

// Binarized MLP: 16384x1024 -> 2048 -> 2048 -> 2048 -> 2.
// All hidden matmuls are +/-1 x +/-1 -> XOR+popcount on bit-packed rows.
// dot over D elems = D - 2*popc(a^b). BN+binq folds to per-neuron
// threshold: bit = (alpha*c + beta) >= 0 with alpha = g*rsqrt(v+eps),
// beta = b - m*alpha. Final layer emits exact integers as float32.

typedef unsigned long long u64;

static constexpr int THREADS = 256;
static constexpr int Bsz = 16384;
static constexpr int Din = 1024;   // K words = 16
static constexpr int Hid = 2048;   // K words = 32

// ---------------- packing: sign-threshold -> bitplane via wave ballot ------
__global__ void pack_kernel(const float* __restrict__ src, u64* __restrict__ dst,
                            int n, float thr) {
  int idx = blockIdx.x * THREADS + threadIdx.x;
  int pred = (idx < n) && (src[idx] >= thr);
  u64 m = __ballot(pred);                    // bit L = lane L's pred (wave64)
  if ((threadIdx.x & 63) == 0 && idx < n) dst[idx >> 6] = m;
}

// ---------------- fold BN into (alpha, beta) per neuron --------------------
__global__ void bnprep_kernel(const float* __restrict__ g, const float* __restrict__ b,
                              const float* __restrict__ m, const float* __restrict__ v,
                              float* __restrict__ alpha, float* __restrict__ beta, int n) {
  int i = blockIdx.x * THREADS + threadIdx.x;
  if (i < n) {
    float a = g[i] / sqrtf(v[i] + 1e-5f);
    alpha[i] = a;
    beta[i] = b[i] - m[i] * a;
  }
}

// ---------------- bit-GEMM layer: C = Pin x PW^T, BN, binarize, repack -----
// Block tile 128(b) x 64(h); whole K (16 or 32 u64 words) staged in LDS.
// Thread tile 8x4. Padded LDS rows (KW+1) to stagger banks.
template <int KW>
__global__ __launch_bounds__(256, 3) void layer_kernel(
    const u64* __restrict__ Pin, const u64* __restrict__ PW,
    const float* __restrict__ alpha, const float* __restrict__ beta,
    u64* __restrict__ Pout, int H) {
  constexpr int BM = 128, BNc = 64, KP = KW + 1;
  __shared__ u64 sA[BM * KP];
  __shared__ u64 sB[BNc * KP];   // byte-tile (128x64 = 8 KB) overlaid post-compute
  const int tid = threadIdx.x;
  const int h0 = blockIdx.x * BNc;
  const int b0 = blockIdx.y * BM;

  for (int i = tid; i < BM * KW; i += THREADS) {
    int r = i / KW, c = i & (KW - 1);
    sA[r * KP + c] = Pin[(size_t)(b0 + r) * KW + c];
  }
  for (int i = tid; i < BNc * KW; i += THREADS) {
    int r = i / KW, c = i & (KW - 1);
    sB[r * KP + c] = PW[(size_t)(h0 + r) * KW + c];
  }
  __syncthreads();

  const int tx = tid & 15, ty = tid >> 4;
  const int row0 = ty * 8, col0 = tx * 4;

  unsigned acc[8][4];
#pragma unroll
  for (int i = 0; i < 8; ++i)
#pragma unroll
    for (int j = 0; j < 4; ++j) acc[i][j] = 0;

#pragma unroll 4
  for (int k = 0; k < KW; ++k) {
    u64 a[8], bw[4];
#pragma unroll
    for (int i = 0; i < 8; ++i) a[i] = sA[(row0 + i) * KP + k];
#pragma unroll
    for (int j = 0; j < 4; ++j) bw[j] = sB[(col0 + j) * KP + k];
#pragma unroll
    for (int i = 0; i < 8; ++i)
#pragma unroll
      for (int j = 0; j < 4; ++j) acc[i][j] += __popcll(a[i] ^ bw[j]);
  }

  __syncthreads();                         // everyone done reading sB
  unsigned char* sbytes = (unsigned char*)sB;

  float al[4], be[4];
#pragma unroll
  for (int j = 0; j < 4; ++j) {
    al[j] = alpha[h0 + col0 + j];
    be[j] = beta[h0 + col0 + j];
  }
  const float Df = (float)(KW * 64);
#pragma unroll
  for (int i = 0; i < 8; ++i)
#pragma unroll
    for (int j = 0; j < 4; ++j) {
      float c = Df - 2.0f * (float)acc[i][j];
      sbytes[(row0 + i) * BNc + (col0 + j)] =
          (fmaf(al[j], c, be[j]) >= 0.0f) ? 1 : 0;
    }
  __syncthreads();

  // repack: wave w handles 32 rows; lane L = column h0+L
  const int lane = tid & 63;
  const int wv = tid >> 6;
  const int HW = H >> 6;
  for (int r = wv * 32; r < wv * 32 + 32; ++r) {
    u64 m = __ballot(sbytes[r * BNc + lane] != 0);
    if (lane == 0) Pout[(size_t)(b0 + r) * HW + (h0 >> 6)] = m;
  }
}

// ---------------- final 2-neuron layer: exact ints as float ----------------
__global__ void final_kernel(const u64* __restrict__ P, const u64* __restrict__ PWo,
                             float* __restrict__ out, int B) {
  __shared__ u64 sw[64];
  if (threadIdx.x < 64) sw[threadIdx.x] = PWo[threadIdx.x];
  __syncthreads();
  int b = blockIdx.x * THREADS + threadIdx.x;
  if (b >= B) return;
  unsigned a0 = 0, a1 = 0;
#pragma unroll
  for (int k = 0; k < 32; ++k) {
    u64 a = P[(size_t)b * 32 + k];
    a0 += __popcll(a ^ sw[k]);
    a1 += __popcll(a ^ sw[32 + k]);
  }
  out[b * 2 + 0] = (float)(2048 - 2 * (int)a0);
  out[b * 2 + 1] = (float)(2048 - 2 * (int)a1);
}

extern "C" void kernel_launch(void* const* d_in, const int* in_sizes, int n_in,
                              void* d_out, int out_size, void* d_ws, size_t ws_size,
                              hipStream_t stream) {
  const float* x    = (const float*)d_in[0];
  const float* w1   = (const float*)d_in[1];
  const float* g1   = (const float*)d_in[2];
  const float* b1   = (const float*)d_in[3];
  const float* m1   = (const float*)d_in[4];
  const float* v1   = (const float*)d_in[5];
  const float* w2   = (const float*)d_in[6];
  const float* g2   = (const float*)d_in[7];
  const float* b2   = (const float*)d_in[8];
  const float* m2   = (const float*)d_in[9];
  const float* v2   = (const float*)d_in[10];
  const float* w3   = (const float*)d_in[11];
  const float* g3   = (const float*)d_in[12];
  const float* b3   = (const float*)d_in[13];
  const float* m3   = (const float*)d_in[14];
  const float* v3   = (const float*)d_in[15];
  const float* wout = (const float*)d_in[16];
  float* out = (float*)d_out;

  char* base = (char*)d_ws;
  size_t off = 0;
  auto take = [&](size_t bytes) -> char* {
    char* p = base + off;
    off += (bytes + 255) & ~(size_t)255;
    return p;
  };
  u64* P0  = (u64*)take((size_t)Bsz * 16 * 8);   // 2 MB
  u64* P1  = (u64*)take((size_t)Bsz * 32 * 8);   // 4 MB
  u64* P2  = (u64*)take((size_t)Bsz * 32 * 8);
  u64* P3  = (u64*)take((size_t)Bsz * 32 * 8);
  u64* PW1 = (u64*)take((size_t)Hid * 16 * 8);
  u64* PW2 = (u64*)take((size_t)Hid * 32 * 8);
  u64* PW3 = (u64*)take((size_t)Hid * 32 * 8);
  u64* PWo = (u64*)take(64 * 8);
  float* a1 = (float*)take(Hid * 4);
  float* be1 = (float*)take(Hid * 4);
  float* a2 = (float*)take(Hid * 4);
  float* be2 = (float*)take(Hid * 4);
  float* a3 = (float*)take(Hid * 4);
  float* be3 = (float*)take(Hid * 4);

  auto blocks = [](int n) { return (n + THREADS - 1) / THREADS; };

  // pack activations (threshold 0.5: binq(2x-1) >= 0 <=> x >= 0.5) + weights
  pack_kernel<<<blocks(Bsz * Din), THREADS, 0, stream>>>(x, P0, Bsz * Din, 0.5f);
  pack_kernel<<<blocks(Hid * Din), THREADS, 0, stream>>>(w1, PW1, Hid * Din, 0.0f);
  pack_kernel<<<blocks(Hid * Hid), THREADS, 0, stream>>>(w2, PW2, Hid * Hid, 0.0f);
  pack_kernel<<<blocks(Hid * Hid), THREADS, 0, stream>>>(w3, PW3, Hid * Hid, 0.0f);
  pack_kernel<<<blocks(2 * Hid), THREADS, 0, stream>>>(wout, PWo, 2 * Hid, 0.0f);

  bnprep_kernel<<<blocks(Hid), THREADS, 0, stream>>>(g1, b1, m1, v1, a1, be1, Hid);
  bnprep_kernel<<<blocks(Hid), THREADS, 0, stream>>>(g2, b2, m2, v2, a2, be2, Hid);
  bnprep_kernel<<<blocks(Hid), THREADS, 0, stream>>>(g3, b3, m3, v3, a3, be3, Hid);

  dim3 lgrid(Hid / 64, Bsz / 128);
  layer_kernel<16><<<lgrid, THREADS, 0, stream>>>(P0, PW1, a1, be1, P1, Hid);
  layer_kernel<32><<<lgrid, THREADS, 0, stream>>>(P1, PW2, a2, be2, P2, Hid);
  layer_kernel<32><<<lgrid, THREADS, 0, stream>>>(P2, PW3, a3, be3, P3, Hid);

  final_kernel<<<blocks(Bsz), THREADS, 0, stream>>>(P3, PWo, out, Bsz);
}